// Round 10
// baseline (104.900 us; speedup 1.0000x reference)
//
#include <hip/hip_runtime.h>

typedef float f32x2 __attribute__((ext_vector_type(2)));
typedef float f32x4 __attribute__((ext_vector_type(4)));

#define N_SUB 10
#define SUBSP 10
#define PADG 644     // 640 floats per subgroup basis + 4 pad (bank spread)
#define LDS_F 6440   // 25.8 KB: basis only (no park) -> LDS allows 6 blocks/CU
#define SC 0.03125f  // 2^-5 pre-scale (s=5 squarings)

#define LO2(v4) __builtin_shufflevector(v4, v4, 0, 1)
#define HI2(v4) __builtin_shufflevector(v4, v4, 2, 3)

// ---- Packed-FP32 (VOP3P). pk is THROUGHPUT-NEUTRAL on CDNA4 (round-7
// measurement) but halves issue slots; op_sel broadcast kills splat movs.
//   _L: both result halves use src0.lo    _H: both use src0.hi
#define PK_FMA_L(d, x, y) \
  asm("v_pk_fma_f32 %0, %1, %2, %0 op_sel:[0,0,0] op_sel_hi:[0,1,1]" \
      : "+v"(d) : "v"(x), "v"(y))
#define PK_FMA_H(d, x, y) \
  asm("v_pk_fma_f32 %0, %1, %2, %0 op_sel:[1,0,0] op_sel_hi:[1,1,1]" \
      : "+v"(d) : "v"(x), "v"(y))
#define PK_MUL_L(d, x, y) \
  asm("v_pk_mul_f32 %0, %1, %2 op_sel:[0,0] op_sel_hi:[0,1]" \
      : "=v"(d) : "v"(x), "v"(y))
#define PK_MUL_H(d, x, y) \
  asm("v_pk_mul_f32 %0, %1, %2 op_sel:[1,0] op_sel_hi:[1,1]" \
      : "=v"(d) : "v"(x), "v"(y))

// ---- 8x8 matrix = 32 NAMED f32x2 SSA values: row r, chunk j (cols 2j,2j+1).
// No arrays -> no scratch demotion (round-3 lesson: arrays = 460MB spill).
#define DECLR(M, r) f32x2 M##r##0, M##r##1, M##r##2, M##r##3
#define DECLM(M) \
  DECLR(M,0); DECLR(M,1); DECLR(M,2); DECLR(M,3); \
  DECLR(M,4); DECLR(M,5); DECLR(M,6); DECLR(M,7)

// Z[r][2j..2j+1] = sum_k X[r][k] * Y[k][2j..2j+1]; X element k lives in
// chunk k/2, half k%2 -> alternate _L/_H broadcasts.
#define MMCH(Z, X, Y, r, j)                  \
  PK_MUL_L(Z##r##j, X##r##0, Y##0##j);       \
  PK_FMA_H(Z##r##j, X##r##0, Y##1##j);       \
  PK_FMA_L(Z##r##j, X##r##1, Y##2##j);       \
  PK_FMA_H(Z##r##j, X##r##1, Y##3##j);       \
  PK_FMA_L(Z##r##j, X##r##2, Y##4##j);       \
  PK_FMA_H(Z##r##j, X##r##2, Y##5##j);       \
  PK_FMA_L(Z##r##j, X##r##3, Y##6##j);       \
  PK_FMA_H(Z##r##j, X##r##3, Y##7##j);
#define MMROW(Z, X, Y, r) \
  MMCH(Z,X,Y,r,0) MMCH(Z,X,Y,r,1) MMCH(Z,X,Y,r,2) MMCH(Z,X,Y,r,3)
#define MM(Z, X, Y)                                          \
  MMROW(Z,X,Y,0) MMROW(Z,X,Y,1) MMROW(Z,X,Y,2) MMROW(Z,X,Y,3) \
  MMROW(Z,X,Y,4) MMROW(Z,X,Y,5) MMROW(Z,X,Y,6) MMROW(Z,X,Y,7)

// basis row (k, r), half h, for subgroup at gbase (16B-aligned)
#define BROW(k, r, h) (*(const f32x4*)&smem[gbase + (k)*64 + (r)*8 + (h)*4])

// ---- Build from z-PAIRS: zz = {z[2t], z[2t+1]}*SC in one VGPR pair; the
// op_sel L/H broadcast consumes it directly. One row-step covers basis
// matrices 2t and 2t+1.
#define BLD2ROW(r, t, F0, F1) {                              \
    f32x4 u0 = BROW(2*(t),   r, 0), u1 = BROW(2*(t),   r, 1);\
    f32x4 w0 = BROW(2*(t)+1, r, 0), w1 = BROW(2*(t)+1, r, 1);\
    F0(A##r##0, zz, LO2(u0)); F1(A##r##0, zz, LO2(w0));      \
    F0(A##r##1, zz, HI2(u0)); F1(A##r##1, zz, HI2(w0));      \
    F0(A##r##2, zz, LO2(u1)); F1(A##r##2, zz, LO2(w1));      \
    F0(A##r##3, zz, HI2(u1)); F1(A##r##3, zz, HI2(w1)); }
#define BLD2MAT(t, F0, F1)                                   \
  BLD2ROW(0,t,F0,F1) BLD2ROW(1,t,F0,F1) BLD2ROW(2,t,F0,F1)   \
  BLD2ROW(3,t,F0,F1) BLD2ROW(4,t,F0,F1) BLD2ROW(5,t,F0,F1)   \
  BLD2ROW(6,t,F0,F1) BLD2ROW(7,t,F0,F1)

// P = ca*X + cb*Y ; P = cc*X + Q
#define LCROW(P, X, Y, ca, cb, r)                            \
  P##r##0 = (ca)*X##r##0 + (cb)*Y##r##0;                     \
  P##r##1 = (ca)*X##r##1 + (cb)*Y##r##1;                     \
  P##r##2 = (ca)*X##r##2 + (cb)*Y##r##2;                     \
  P##r##3 = (ca)*X##r##3 + (cb)*Y##r##3;
#define LC(P, X, Y, ca, cb)                                  \
  LCROW(P,X,Y,ca,cb,0) LCROW(P,X,Y,ca,cb,1) LCROW(P,X,Y,ca,cb,2) \
  LCROW(P,X,Y,ca,cb,3) LCROW(P,X,Y,ca,cb,4) LCROW(P,X,Y,ca,cb,5) \
  LCROW(P,X,Y,ca,cb,6) LCROW(P,X,Y,ca,cb,7)
#define AXROW(P, X, Q, cc, r)                                \
  P##r##0 = (cc)*X##r##0 + Q##r##0;                          \
  P##r##1 = (cc)*X##r##1 + Q##r##1;                          \
  P##r##2 = (cc)*X##r##2 + Q##r##2;                          \
  P##r##3 = (cc)*X##r##3 + Q##r##3;
#define AXPY(P, X, Q, cc)                                    \
  AXROW(P,X,Q,cc,0) AXROW(P,X,Q,cc,1) AXROW(P,X,Q,cc,2)      \
  AXROW(P,X,Q,cc,3) AXROW(P,X,Q,cc,4) AXROW(P,X,Q,cc,5)      \
  AXROW(P,X,Q,cc,6) AXROW(P,X,Q,cc,7)

// diag (r,r): chunk r/2, element r%2
#define ADD_DIAG(M, c)                                       \
  M##00[0] += (c); M##10[1] += (c); M##21[0] += (c); M##31[1] += (c); \
  M##42[0] += (c); M##52[1] += (c); M##63[0] += (c); M##73[1] += (c);

#define STROW(M, r, outp) {                                  \
  f32x4 w0 = __builtin_shufflevector(M##r##0, M##r##1, 0,1,2,3); \
  f32x4 w1 = __builtin_shufflevector(M##r##2, M##r##3, 0,1,2,3); \
  *(f32x4*)((outp) + (r)*8)     = w0;                        \
  *(f32x4*)((outp) + (r)*8 + 4) = w1; }
#define STORE(M, outp)                                       \
  STROW(M,0,outp) STROW(M,1,outp) STROW(M,2,outp) STROW(M,3,outp) \
  STROW(M,4,outp) STROW(M,5,outp) STROW(M,6,outp) STROW(M,7,outp)

// exp(M) (M pre-scaled by 2^-5): order-6 Paterson-Stockmeyer + 5 squarings.
#define EXPM(M, outp) {                                      \
    DECLM(S); MM(S, M, M)                                    \
    DECLM(P); LC(P, S, M, c6, c5) ADD_DIAG(P, c4)            \
    DECLM(Q); MM(Q, S, P)                                    \
    AXPY(P, M, Q, c3) ADD_DIAG(P, c2)                        \
    MM(Q, S, P)                                              \
    AXPY(P, M, Q, 1.0f) ADD_DIAG(P, 1.0f)                    \
    MM(Q, P, P) MM(P, Q, Q) MM(Q, P, P) MM(P, Q, Q) MM(Q, P, P) \
    STORE(Q, outp) }

// waves_per_eu(2,4): ROUND-9 FINDING — the attr's MAX is honored as a hard
// runtime occupancy cap (round 8 (4,4) measured 38% occ; every (2,2) round
// pinned at ~19% even when VGPR=128 + LDS=26KB allow 16 waves/CU). min=2
// keeps the register guarantee that reliably yields the proven no-spill
// 128-VGPR codegen (round 8's min=4 forced the 64-VGPR tier -> 700MB spill);
// max=4 lifts the cap so the resource-permitted 4 waves/EU become resident.
__global__ __launch_bounds__(256)
__attribute__((amdgpu_waves_per_eu(2, 4)))
void lie_expm_kernel(const float* __restrict__ z,
                     const float* __restrict__ basis,
                     float* __restrict__ out) {
  __shared__ __align__(16) float smem[LDS_F];
  const int tid = threadIdx.x;

  // ---- Stage basis (vec4), padded per subgroup: g*644 + r.
  for (int i4 = tid; i4 < 1600; i4 += 256) {
    int g = i4 / 160;
    int r4 = i4 - g * 160;
    *(f32x4*)&smem[g * PADG + r4 * 4] = *(const f32x4*)&basis[i4 * 4];
  }
  __syncthreads();

  const int m = blockIdx.x * 256 + tid;  // matrix id = b*10 + g (grid exact)
  const int g = m % N_SUB;
  const int gbase = g * PADG;
  // z row for this matrix: 10 floats at z + m*10 (40B -> 8B-aligned f32x2)
  const f32x2* zv = (const f32x2*)(z + (size_t)m * SUBSP);

  // ---- Build A = sum_k z_k * B_k, pre-scaled by 2^-5. z consumed as pairs.
  DECLM(A);
  { const f32x2 zz = zv[0] * SC; BLD2MAT(0, PK_MUL_L, PK_FMA_H) }
  { const f32x2 zz = zv[1] * SC; BLD2MAT(1, PK_FMA_L, PK_FMA_H) }
  { const f32x2 zz = zv[2] * SC; BLD2MAT(2, PK_FMA_L, PK_FMA_H) }
  { const f32x2 zz = zv[3] * SC; BLD2MAT(3, PK_FMA_L, PK_FMA_H) }
  { const f32x2 zz = zv[4] * SC; BLD2MAT(4, PK_FMA_L, PK_FMA_H) }

  const float c2 = 0.5f, c3 = 1.0f / 6.0f, c4 = 1.0f / 24.0f,
              c5 = 1.0f / 120.0f, c6 = 1.0f / 720.0f;

  EXPM(A, out + (size_t)m * 64);
}

extern "C" void kernel_launch(void* const* d_in, const int* in_sizes, int n_in,
                              void* d_out, int out_size, void* d_ws, size_t ws_size,
                              hipStream_t stream) {
  const float* z = (const float*)d_in[0];
  const float* basis = (const float*)d_in[1];
  float* out = (float*)d_out;

  const int batch = in_sizes[0] / (N_SUB * SUBSP);  // 65536
  const int n_mat = batch * N_SUB;                  // 655360
  const int grid = n_mat / 256;                     // 2560 (exact)

  lie_expm_kernel<<<grid, 256, 0, stream>>>(z, basis, out);
}

// Round 11
// 96.982 us; speedup vs baseline: 1.0816x; 1.0816x over previous
//
#include <hip/hip_runtime.h>

typedef float f32x2 __attribute__((ext_vector_type(2)));
typedef float f32x4 __attribute__((ext_vector_type(4)));
typedef float f32x16 __attribute__((ext_vector_type(16)));

#define N_SUB 10
#define SUBSP 10
#define SC 0.03125f  // 2^-5 pre-scale (s=5 squarings)

// ================= scalar-pipe basis loads =================
// Round-10 diagnosis: 160 ds_read_b128/matrix = ~32us of serialized per-CU
// LDS-pipe time that doesn't overlap at 2 waves/EU. With one g per WAVE the
// basis is wave-uniform -> stream it through SGPRs on the scalar pipe and
// feed v_pk_fma_f32's single legal scalar operand. LDS usage: ZERO.
#define SLOAD16(dst, base, imm) \
  asm volatile("s_load_dwordx16 %0, %1, %2" \
               : "=s"(dst) : "s"(base), "i"(imm))
// waitcnt DEFINES the loaded regs ("+s") so consumers are dataflow-ordered
// behind it (rule-18-proof: no reliance on "memory" clobber ordering).
#define SWAIT4(a, b, c, d) \
  asm volatile("s_waitcnt lgkmcnt(0)" \
               : "+s"(a), "+s"(b), "+s"(c), "+s"(d))

// even-aligned SGPR pair (2j, 2j+1) extracted from an x16 scalar vector
#define SPAIR(V, j) __builtin_shufflevector(V, V, 2*(j), 2*(j)+1)

// ================= packed-FP32 primitives =================
// pk is THROUGHPUT-NEUTRAL on CDNA4 (round-7) but halves issue slots.
//   _L: both result halves use src0.lo    _H: both use src0.hi
// Build variants take src1 from SGPRs (VOP3P: max 1 scalar operand OK).
#define PKB_FMA_L(d, zp, sp) \
  asm("v_pk_fma_f32 %0, %1, %2, %0 op_sel:[0,0,0] op_sel_hi:[0,1,1]" \
      : "+v"(d) : "v"(zp), "s"(sp))
#define PKB_FMA_H(d, zp, sp) \
  asm("v_pk_fma_f32 %0, %1, %2, %0 op_sel:[1,0,0] op_sel_hi:[1,1,1]" \
      : "+v"(d) : "v"(zp), "s"(sp))
#define PKB_MUL_L(d, zp, sp) \
  asm("v_pk_mul_f32 %0, %1, %2 op_sel:[0,0] op_sel_hi:[0,1]" \
      : "=v"(d) : "v"(zp), "s"(sp))
// MM variants: all-VGPR (unchanged from rounds 7-10, proven no-spill).
#define PK_FMA_L(d, x, y) \
  asm("v_pk_fma_f32 %0, %1, %2, %0 op_sel:[0,0,0] op_sel_hi:[0,1,1]" \
      : "+v"(d) : "v"(x), "v"(y))
#define PK_FMA_H(d, x, y) \
  asm("v_pk_fma_f32 %0, %1, %2, %0 op_sel:[1,0,0] op_sel_hi:[1,1,1]" \
      : "+v"(d) : "v"(x), "v"(y))
#define PK_MUL_L(d, x, y) \
  asm("v_pk_mul_f32 %0, %1, %2 op_sel:[0,0] op_sel_hi:[0,1]" \
      : "=v"(d) : "v"(x), "v"(y))

// ---- 8x8 matrix = 32 NAMED f32x2 SSA values: row r, chunk j (cols 2j,2j+1).
// No arrays -> no scratch demotion (round-3 lesson: arrays = 460MB spill).
#define DECLR(M, r) f32x2 M##r##0, M##r##1, M##r##2, M##r##3
#define DECLM(M) \
  DECLR(M,0); DECLR(M,1); DECLR(M,2); DECLR(M,3); \
  DECLR(M,4); DECLR(M,5); DECLR(M,6); DECLR(M,7)

// Z[r][2j..2j+1] = sum_k X[r][k] * Y[k][2j..2j+1]; X element k lives in
// chunk k/2, half k%2 -> alternate _L/_H broadcasts.
#define MMCH(Z, X, Y, r, j)                  \
  PK_MUL_L(Z##r##j, X##r##0, Y##0##j);       \
  PK_FMA_H(Z##r##j, X##r##0, Y##1##j);       \
  PK_FMA_L(Z##r##j, X##r##1, Y##2##j);       \
  PK_FMA_H(Z##r##j, X##r##1, Y##3##j);       \
  PK_FMA_L(Z##r##j, X##r##2, Y##4##j);       \
  PK_FMA_H(Z##r##j, X##r##2, Y##5##j);       \
  PK_FMA_L(Z##r##j, X##r##3, Y##6##j);       \
  PK_FMA_H(Z##r##j, X##r##3, Y##7##j);
#define MMROW(Z, X, Y, r) \
  MMCH(Z,X,Y,r,0) MMCH(Z,X,Y,r,1) MMCH(Z,X,Y,r,2) MMCH(Z,X,Y,r,3)
#define MM(Z, X, Y)                                          \
  MMROW(Z,X,Y,0) MMROW(Z,X,Y,1) MMROW(Z,X,Y,2) MMROW(Z,X,Y,3) \
  MMROW(Z,X,Y,4) MMROW(Z,X,Y,5) MMROW(Z,X,Y,6) MMROW(Z,X,Y,7)

// ---- Build: one k-step = 64 basis floats s_loaded into 4 x16 SGPR vectors.
// Kv chunk h covers elements 16h..16h+15 = rows 2h, 2h+1 (8 floats each).
#define BLDK2(F, Kv, ra, rb)                                  \
  F(A##ra##0, zz, SPAIR(Kv,0)); F(A##ra##1, zz, SPAIR(Kv,1)); \
  F(A##ra##2, zz, SPAIR(Kv,2)); F(A##ra##3, zz, SPAIR(Kv,3)); \
  F(A##rb##0, zz, SPAIR(Kv,4)); F(A##rb##1, zz, SPAIR(Kv,5)); \
  F(A##rb##2, zz, SPAIR(Kv,6)); F(A##rb##3, zz, SPAIR(Kv,7));
#define KSTEP(koff, F)                                        \
  {                                                           \
    f32x16 K0, K1, K2, K3;                                    \
    SLOAD16(K0, bp, (koff)*256 + 0);                          \
    SLOAD16(K1, bp, (koff)*256 + 64);                         \
    SLOAD16(K2, bp, (koff)*256 + 128);                        \
    SLOAD16(K3, bp, (koff)*256 + 192);                        \
    SWAIT4(K0, K1, K2, K3);                                   \
    BLDK2(F, K0, 0, 1) BLDK2(F, K1, 2, 3)                     \
    BLDK2(F, K2, 4, 5) BLDK2(F, K3, 6, 7)                     \
  }

// P = ca*X + cb*Y ; P = cc*X + Q
#define LCROW(P, X, Y, ca, cb, r)                            \
  P##r##0 = (ca)*X##r##0 + (cb)*Y##r##0;                     \
  P##r##1 = (ca)*X##r##1 + (cb)*Y##r##1;                     \
  P##r##2 = (ca)*X##r##2 + (cb)*Y##r##2;                     \
  P##r##3 = (ca)*X##r##3 + (cb)*Y##r##3;
#define LC(P, X, Y, ca, cb)                                  \
  LCROW(P,X,Y,ca,cb,0) LCROW(P,X,Y,ca,cb,1) LCROW(P,X,Y,ca,cb,2) \
  LCROW(P,X,Y,ca,cb,3) LCROW(P,X,Y,ca,cb,4) LCROW(P,X,Y,ca,cb,5) \
  LCROW(P,X,Y,ca,cb,6) LCROW(P,X,Y,ca,cb,7)
#define AXROW(P, X, Q, cc, r)                                \
  P##r##0 = (cc)*X##r##0 + Q##r##0;                          \
  P##r##1 = (cc)*X##r##1 + Q##r##1;                          \
  P##r##2 = (cc)*X##r##2 + Q##r##2;                          \
  P##r##3 = (cc)*X##r##3 + Q##r##3;
#define AXPY(P, X, Q, cc)                                    \
  AXROW(P,X,Q,cc,0) AXROW(P,X,Q,cc,1) AXROW(P,X,Q,cc,2)      \
  AXROW(P,X,Q,cc,3) AXROW(P,X,Q,cc,4) AXROW(P,X,Q,cc,5)      \
  AXROW(P,X,Q,cc,6) AXROW(P,X,Q,cc,7)

// diag (r,r): chunk r/2, element r%2
#define ADD_DIAG(M, c)                                       \
  M##00[0] += (c); M##10[1] += (c); M##21[0] += (c); M##31[1] += (c); \
  M##42[0] += (c); M##52[1] += (c); M##63[0] += (c); M##73[1] += (c);

#define STROW(M, r, outp) {                                  \
  f32x4 w0 = __builtin_shufflevector(M##r##0, M##r##1, 0,1,2,3); \
  f32x4 w1 = __builtin_shufflevector(M##r##2, M##r##3, 0,1,2,3); \
  *(f32x4*)((outp) + (r)*8)     = w0;                        \
  *(f32x4*)((outp) + (r)*8 + 4) = w1; }
#define STORE(M, outp)                                       \
  STROW(M,0,outp) STROW(M,1,outp) STROW(M,2,outp) STROW(M,3,outp) \
  STROW(M,4,outp) STROW(M,5,outp) STROW(M,6,outp) STROW(M,7,outp)

// exp(M) (M pre-scaled by 2^-5): order-6 Paterson-Stockmeyer + 5 squarings.
#define EXPM(M, outp) {                                      \
    DECLM(S); MM(S, M, M)                                    \
    DECLM(P); LC(P, S, M, c6, c5) ADD_DIAG(P, c4)            \
    DECLM(Q); MM(Q, S, P)                                    \
    AXPY(P, M, Q, c3) ADD_DIAG(P, c2)                        \
    MM(Q, S, P)                                              \
    AXPY(P, M, Q, 1.0f) ADD_DIAG(P, 1.0f)                    \
    MM(Q, P, P) MM(P, Q, Q) MM(Q, P, P) MM(P, Q, Q) MM(Q, P, P) \
    STORE(Q, outp) }

// waves_per_eu(2,4): round-10-proven safe codegen for this shape (VGPR=108,
// zero spill). NO LDS in this kernel (basis via scalar pipe, no park, no
// __syncthreads) -> residency limited by VGPR only.
__global__ __launch_bounds__(256)
__attribute__((amdgpu_waves_per_eu(2, 4)))
void lie_expm_kernel(const float* __restrict__ z,
                     const float* __restrict__ basis,
                     float* __restrict__ out) {
  const int tid = threadIdx.x;
  const int lane = tid & 63;
  const int W = blockIdx.x * 4 + (tid >> 6);           // global wave id
  // One subgroup g per WAVE (basis becomes wave-uniform); 64 consecutive
  // batch rows per wave. readfirstlane makes uniformity provable -> SGPRs.
  const int g  = __builtin_amdgcn_readfirstlane(W % N_SUB);
  const int bb = __builtin_amdgcn_readfirstlane(W / N_SUB) * 64;
  const int b  = bb + lane;

  const float* bp = basis + g * (SUBSP * 64);          // uniform -> SGPR pair

  // z row for (b, g): 10 floats at z + b*100 + g*10 (8B-aligned), as 5 pairs.
  const float* zrow = z + (size_t)b * (N_SUB * SUBSP) + g * SUBSP;
  const f32x2 zv0 = *(const f32x2*)(zrow + 0) * SC;
  const f32x2 zv1 = *(const f32x2*)(zrow + 2) * SC;
  const f32x2 zv2 = *(const f32x2*)(zrow + 4) * SC;
  const f32x2 zv3 = *(const f32x2*)(zrow + 6) * SC;
  const f32x2 zv4 = *(const f32x2*)(zrow + 8) * SC;

  // ---- Build A = sum_k z_k * B_k (pre-scaled): 40 s_loads + 320 pk-FMA.
  // k even uses pair.lo (_L), k odd uses pair.hi (_H).
  DECLM(A);
  { const f32x2 zz = zv0; KSTEP(0, PKB_MUL_L) }
  { const f32x2 zz = zv0; KSTEP(1, PKB_FMA_H) }
  { const f32x2 zz = zv1; KSTEP(2, PKB_FMA_L) }
  { const f32x2 zz = zv1; KSTEP(3, PKB_FMA_H) }
  { const f32x2 zz = zv2; KSTEP(4, PKB_FMA_L) }
  { const f32x2 zz = zv2; KSTEP(5, PKB_FMA_H) }
  { const f32x2 zz = zv3; KSTEP(6, PKB_FMA_L) }
  { const f32x2 zz = zv3; KSTEP(7, PKB_FMA_H) }
  { const f32x2 zz = zv4; KSTEP(8, PKB_FMA_L) }
  { const f32x2 zz = zv4; KSTEP(9, PKB_FMA_H) }

  const float c2 = 0.5f, c3 = 1.0f / 6.0f, c4 = 1.0f / 24.0f,
              c5 = 1.0f / 120.0f, c6 = 1.0f / 720.0f;

  // out row for matrix m = b*10 + g: 256B contiguous per lane.
  float* outp = out + ((size_t)b * N_SUB + g) * 64;
  EXPM(A, outp);
}

extern "C" void kernel_launch(void* const* d_in, const int* in_sizes, int n_in,
                              void* d_out, int out_size, void* d_ws, size_t ws_size,
                              hipStream_t stream) {
  const float* z = (const float*)d_in[0];
  const float* basis = (const float*)d_in[1];
  float* out = (float*)d_out;

  const int batch = in_sizes[0] / (N_SUB * SUBSP);  // 65536
  const int n_waves = batch / 64 * N_SUB;           // 10240
  const int grid = n_waves / 4;                     // 2560 blocks x 4 waves

  lie_expm_kernel<<<grid, 256, 0, stream>>>(z, basis, out);
}

// Round 12
// 91.034 us; speedup vs baseline: 1.1523x; 1.0653x over previous
//
#include <hip/hip_runtime.h>

typedef float f32x2 __attribute__((ext_vector_type(2)));
typedef float f32x4 __attribute__((ext_vector_type(4)));
typedef float f32x16 __attribute__((ext_vector_type(16)));

#define N_SUB 10
#define SUBSP 10
#define SC 0.125f  // 2^-3 pre-scale (s=3 squarings, order-8 PS)

// ================= scalar-pipe basis loads =================
// One subgroup g per WAVE -> basis is wave-uniform -> stream via SGPRs on
// the scalar pipe (round-11 structure, proven: LDS=0, no spill).
#define SLOAD16(dst, base, imm) \
  asm volatile("s_load_dwordx16 %0, %1, %2" \
               : "=s"(dst) : "s"(base), "i"(imm))
// waitcnt DEFINES the loaded regs ("+s") so consumers are dataflow-ordered
// behind it (rule-18-proof: no reliance on "memory" clobber ordering).
#define SWAIT4(a, b, c, d) \
  asm volatile("s_waitcnt lgkmcnt(0)" \
               : "+s"(a), "+s"(b), "+s"(c), "+s"(d))

// even-aligned SGPR pair (2j, 2j+1) extracted from an x16 scalar vector
#define SPAIR(V, j) __builtin_shufflevector(V, V, 2*(j), 2*(j)+1)

// ================= packed-FP32 primitives =================
// MEASURED (r6-r11 busy-time accounting): v_pk_fma_f32 = 4 cyc (2 FMA/lane)
// = same FLOP rate as scalar v_fmac (2 cyc, 1 FMA). pk kept: halves instr
// count/code size; op_sel broadcast kills splat movs.
//   _L: both result halves use src0.lo    _H: both use src0.hi
#define PKB_FMA_L(d, zp, sp) \
  asm("v_pk_fma_f32 %0, %1, %2, %0 op_sel:[0,0,0] op_sel_hi:[0,1,1]" \
      : "+v"(d) : "v"(zp), "s"(sp))
#define PKB_FMA_H(d, zp, sp) \
  asm("v_pk_fma_f32 %0, %1, %2, %0 op_sel:[1,0,0] op_sel_hi:[1,1,1]" \
      : "+v"(d) : "v"(zp), "s"(sp))
#define PKB_MUL_L(d, zp, sp) \
  asm("v_pk_mul_f32 %0, %1, %2 op_sel:[0,0] op_sel_hi:[0,1]" \
      : "=v"(d) : "v"(zp), "s"(sp))
#define PK_FMA_L(d, x, y) \
  asm("v_pk_fma_f32 %0, %1, %2, %0 op_sel:[0,0,0] op_sel_hi:[0,1,1]" \
      : "+v"(d) : "v"(x), "v"(y))
#define PK_FMA_H(d, x, y) \
  asm("v_pk_fma_f32 %0, %1, %2, %0 op_sel:[1,0,0] op_sel_hi:[1,1,1]" \
      : "+v"(d) : "v"(x), "v"(y))
#define PK_MUL_L(d, x, y) \
  asm("v_pk_mul_f32 %0, %1, %2 op_sel:[0,0] op_sel_hi:[0,1]" \
      : "=v"(d) : "v"(x), "v"(y))

// ---- 8x8 matrix = 32 NAMED f32x2 SSA values: row r, chunk j (cols 2j,2j+1).
// No arrays -> no scratch demotion (round-3 lesson: arrays = 460MB spill).
#define DECLR(M, r) f32x2 M##r##0, M##r##1, M##r##2, M##r##3
#define DECLM(M) \
  DECLR(M,0); DECLR(M,1); DECLR(M,2); DECLR(M,3); \
  DECLR(M,4); DECLR(M,5); DECLR(M,6); DECLR(M,7)

// Z[r][2j..2j+1] = sum_k X[r][k] * Y[k][2j..2j+1]; X element k lives in
// chunk k/2, half k%2 -> alternate _L/_H broadcasts.
#define MMCH(Z, X, Y, r, j)                  \
  PK_MUL_L(Z##r##j, X##r##0, Y##0##j);       \
  PK_FMA_H(Z##r##j, X##r##0, Y##1##j);       \
  PK_FMA_L(Z##r##j, X##r##1, Y##2##j);       \
  PK_FMA_H(Z##r##j, X##r##1, Y##3##j);       \
  PK_FMA_L(Z##r##j, X##r##2, Y##4##j);       \
  PK_FMA_H(Z##r##j, X##r##2, Y##5##j);       \
  PK_FMA_L(Z##r##j, X##r##3, Y##6##j);       \
  PK_FMA_H(Z##r##j, X##r##3, Y##7##j);
#define MMROW(Z, X, Y, r) \
  MMCH(Z,X,Y,r,0) MMCH(Z,X,Y,r,1) MMCH(Z,X,Y,r,2) MMCH(Z,X,Y,r,3)
#define MM(Z, X, Y)                                          \
  MMROW(Z,X,Y,0) MMROW(Z,X,Y,1) MMROW(Z,X,Y,2) MMROW(Z,X,Y,3) \
  MMROW(Z,X,Y,4) MMROW(Z,X,Y,5) MMROW(Z,X,Y,6) MMROW(Z,X,Y,7)

// ---- Build: one k-step = 64 basis floats s_loaded into 4 x16 SGPR vectors.
#define BLDK2(F, Kv, ra, rb)                                  \
  F(A##ra##0, zz, SPAIR(Kv,0)); F(A##ra##1, zz, SPAIR(Kv,1)); \
  F(A##ra##2, zz, SPAIR(Kv,2)); F(A##ra##3, zz, SPAIR(Kv,3)); \
  F(A##rb##0, zz, SPAIR(Kv,4)); F(A##rb##1, zz, SPAIR(Kv,5)); \
  F(A##rb##2, zz, SPAIR(Kv,6)); F(A##rb##3, zz, SPAIR(Kv,7));
#define KSTEP(koff, F)                                        \
  {                                                           \
    f32x16 K0, K1, K2, K3;                                    \
    SLOAD16(K0, bp, (koff)*256 + 0);                          \
    SLOAD16(K1, bp, (koff)*256 + 64);                         \
    SLOAD16(K2, bp, (koff)*256 + 128);                        \
    SLOAD16(K3, bp, (koff)*256 + 192);                        \
    SWAIT4(K0, K1, K2, K3);                                   \
    BLDK2(F, K0, 0, 1) BLDK2(F, K1, 2, 3)                     \
    BLDK2(F, K2, 4, 5) BLDK2(F, K3, 6, 7)                     \
  }

// P = ca*X + cb*Y ; P = cc*X + Q
#define LCROW(P, X, Y, ca, cb, r)                            \
  P##r##0 = (ca)*X##r##0 + (cb)*Y##r##0;                     \
  P##r##1 = (ca)*X##r##1 + (cb)*Y##r##1;                     \
  P##r##2 = (ca)*X##r##2 + (cb)*Y##r##2;                     \
  P##r##3 = (ca)*X##r##3 + (cb)*Y##r##3;
#define LC(P, X, Y, ca, cb)                                  \
  LCROW(P,X,Y,ca,cb,0) LCROW(P,X,Y,ca,cb,1) LCROW(P,X,Y,ca,cb,2) \
  LCROW(P,X,Y,ca,cb,3) LCROW(P,X,Y,ca,cb,4) LCROW(P,X,Y,ca,cb,5) \
  LCROW(P,X,Y,ca,cb,6) LCROW(P,X,Y,ca,cb,7)
#define AXROW(P, X, Q, cc, r)                                \
  P##r##0 = (cc)*X##r##0 + Q##r##0;                          \
  P##r##1 = (cc)*X##r##1 + Q##r##1;                          \
  P##r##2 = (cc)*X##r##2 + Q##r##2;                          \
  P##r##3 = (cc)*X##r##3 + Q##r##3;
#define AXPY(P, X, Q, cc)                                    \
  AXROW(P,X,Q,cc,0) AXROW(P,X,Q,cc,1) AXROW(P,X,Q,cc,2)      \
  AXROW(P,X,Q,cc,3) AXROW(P,X,Q,cc,4) AXROW(P,X,Q,cc,5)      \
  AXROW(P,X,Q,cc,6) AXROW(P,X,Q,cc,7)

// diag (r,r): chunk r/2, element r%2
#define ADD_DIAG(M, c)                                       \
  M##00[0] += (c); M##10[1] += (c); M##21[0] += (c); M##31[1] += (c); \
  M##42[0] += (c); M##52[1] += (c); M##63[0] += (c); M##73[1] += (c);

#define STROW(M, r, outp) {                                  \
  f32x4 w0 = __builtin_shufflevector(M##r##0, M##r##1, 0,1,2,3); \
  f32x4 w1 = __builtin_shufflevector(M##r##2, M##r##3, 0,1,2,3); \
  *(f32x4*)((outp) + (r)*8)     = w0;                        \
  *(f32x4*)((outp) + (r)*8 + 4) = w1; }
#define STORE(M, outp)                                       \
  STROW(M,0,outp) STROW(M,1,outp) STROW(M,2,outp) STROW(M,3,outp) \
  STROW(M,4,outp) STROW(M,5,outp) STROW(M,6,outp) STROW(M,7,outp)

// exp(M) (M pre-scaled by 2^-3): ORDER-8 Paterson-Stockmeyer + 3 squarings
// (7 MMs; round-12 change from order-6/s=5's 8 MMs). Error: 2^3*theta^9/9!,
// theta<=~0.78 worst-case -> ~2e-6 rel. E = c0I+c1A + A2(c2I+c3A +
// A2(c4I+c5A + A2(c6I+c7A+c8A2))).
#define EXPM(M, outp) {                                      \
    DECLM(S); MM(S, M, M)                                    \
    DECLM(P); LC(P, S, M, c8, c7) ADD_DIAG(P, c6)            \
    DECLM(Q); MM(Q, S, P)                                    \
    AXPY(P, M, Q, c5) ADD_DIAG(P, c4)                        \
    MM(Q, S, P)                                              \
    AXPY(P, M, Q, c3) ADD_DIAG(P, c2)                        \
    MM(Q, S, P)                                              \
    AXPY(P, M, Q, 1.0f) ADD_DIAG(P, 1.0f)                    \
    MM(Q, P, P) MM(P, Q, Q) MM(Q, P, P)                      \
    STORE(Q, outp) }

// 64-thread blocks (1 wave): no LDS, no barriers -> nothing needs multi-wave
// blocks. Rounds 6-11: 4-wave blocks run identical straight-line code in
// LOCKSTEP (all waves hit the same lgkm drains / store bursts together,
// VALUBusy pinned ~42%); independent 1-wave blocks stagger naturally.
// waves_per_eu(2,4): proven-safe codegen for this macro set (r10/r11:
// VGPR 108/112, zero spill; r8's min=4 forced 64-VGPR tier = 700MB spill).
__global__ __launch_bounds__(64)
__attribute__((amdgpu_waves_per_eu(2, 4)))
void lie_expm_kernel(const float* __restrict__ z,
                     const float* __restrict__ basis,
                     float* __restrict__ out) {
  const int lane = threadIdx.x & 63;
  const int W = blockIdx.x;            // wave id == block id
  const int g  = W % N_SUB;            // uniform (SGPR) by construction
  const int b  = (W / N_SUB) * 64 + lane;

  const float* bp = basis + g * (SUBSP * 64);   // uniform -> SGPR pair

  // z row for (b, g): 10 floats at z + b*100 + g*10 (8B-aligned), as 5 pairs.
  const float* zrow = z + (size_t)b * (N_SUB * SUBSP) + g * SUBSP;
  const f32x2 zv0 = *(const f32x2*)(zrow + 0) * SC;
  const f32x2 zv1 = *(const f32x2*)(zrow + 2) * SC;
  const f32x2 zv2 = *(const f32x2*)(zrow + 4) * SC;
  const f32x2 zv3 = *(const f32x2*)(zrow + 6) * SC;
  const f32x2 zv4 = *(const f32x2*)(zrow + 8) * SC;

  // ---- Build A = sum_k z_k * B_k (pre-scaled): 40 s_loads + 320 pk-FMA.
  DECLM(A);
  { const f32x2 zz = zv0; KSTEP(0, PKB_MUL_L) }
  { const f32x2 zz = zv0; KSTEP(1, PKB_FMA_H) }
  { const f32x2 zz = zv1; KSTEP(2, PKB_FMA_L) }
  { const f32x2 zz = zv1; KSTEP(3, PKB_FMA_H) }
  { const f32x2 zz = zv2; KSTEP(4, PKB_FMA_L) }
  { const f32x2 zz = zv2; KSTEP(5, PKB_FMA_H) }
  { const f32x2 zz = zv3; KSTEP(6, PKB_FMA_L) }
  { const f32x2 zz = zv3; KSTEP(7, PKB_FMA_H) }
  { const f32x2 zz = zv4; KSTEP(8, PKB_FMA_L) }
  { const f32x2 zz = zv4; KSTEP(9, PKB_FMA_H) }

  const float c2 = 0.5f, c3 = 1.0f / 6.0f, c4 = 1.0f / 24.0f,
              c5 = 1.0f / 120.0f, c6 = 1.0f / 720.0f,
              c7 = 1.0f / 5040.0f, c8 = 1.0f / 40320.0f;

  // out row for matrix m = b*10 + g: 256B contiguous per lane.
  float* outp = out + ((size_t)b * N_SUB + g) * 64;
  EXPM(A, outp);
}

extern "C" void kernel_launch(void* const* d_in, const int* in_sizes, int n_in,
                              void* d_out, int out_size, void* d_ws, size_t ws_size,
                              hipStream_t stream) {
  const float* z = (const float*)d_in[0];
  const float* basis = (const float*)d_in[1];
  float* out = (float*)d_out;

  const int batch = in_sizes[0] / (N_SUB * SUBSP);  // 65536
  const int grid = batch / 64 * N_SUB;              // 10240 1-wave blocks

  lie_expm_kernel<<<grid, 64, 0, stream>>>(z, basis, out);
}